// Round 3
// baseline (190.380 us; speedup 1.0000x reference)
//
#include <hip/hip_runtime.h>

// MeshTokenizer: B=64, NV=8192, NF=16384.
// Outputs concatenated flat as float32:
//   [0] input_ids        64 x 163841   @ 0
//   [1] attention_mask   64 x 163841   @ 10485824
//   [2] codes            64x16384x3x3  @ 20971648
//   [3] discrete_face_coords (==codes) @ 30408832
//   [4] recon_faces      64x1x3x3      @ 39846016
// 159.4 MB writes + ~19 MB reads -> ~28 us write-roofline @6.3 TB/s.

#define B_      64
#define NV_     8192
#define NF_     16384
#define ROW_    (NF_ * 10 + 1)   // 163841 (odd stride -> per-batch dword phase b&3)
#define OFF_IDS   ((size_t)0)
#define OFF_MASK  ((size_t)10485824)
#define OFF_C1    ((size_t)20971648)
#define OFF_C2    ((size_t)30408832)
#define OFF_REC   ((size_t)39846016)

// clang-native vector so __builtin_nontemporal_store accepts it
// (HIP's float4 is a class and is rejected).
typedef float vf4 __attribute__((ext_vector_type(4)));

// One block = 256 consecutive faces of one batch; block's input_ids span is a
// contiguous 2560-float run starting at S = b*163841 + j0*10. Phase p = S&3 is
// baked into the LDS staging offset so readback ds_read_b128 and the global
// dwordx4 nt stores are both 16B-aligned; <=3 head + <=3 tail elems go scalar.
__global__ __launch_bounds__(256) void mesh_tok_kernel(
        const float* __restrict__ verts,
        const int*   __restrict__ faces,
        float*       __restrict__ out) {
    const int t   = threadIdx.x;
    const int blk = blockIdx.x;
    const int b   = blk >> 6;            // batch
    const int j0  = (blk & 63) << 8;     // first face of this block
    const int j   = j0 + t;

    __shared__ __align__(16) float s_ids[2564];   // 2560 + up to 3 phase shift
    __shared__ __align__(16) float s_codes[2304];

    // ---- face indices ----
    const int* fp = faces + ((size_t)b * NF_ + j) * 3;
    const int vidx[3] = { fp[0], fp[1], fp[2] };

    // ---- gather + discretize ----
    const float* vb = verts + (size_t)b * NV_ * 3;
    float code_f[9];
    #pragma unroll
    for (int vi = 0; vi < 3; ++vi) {
        const float* vp = vb + (size_t)vidx[vi] * 3;
        #pragma unroll
        for (int ci = 0; ci < 3; ++ci) {
            // (x-LO)/(HI-LO)*128 - 0.5 == (x+1)*64 - 0.5 bit-exactly
            float q = (vp[ci] + 1.0f) * 64.0f - 0.5f;
            float r = rintf(q);                         // round-half-even
            code_f[vi * 3 + ci] = fminf(fmaxf(r, 0.0f), 127.0f);
        }
    }

    const size_t S  = (size_t)b * ROW_ + (size_t)j0 * 10;  // span start (ids)
    const int    p  = (int)(S & 3);                        // == b & 3
    const int    pp = (4 - p) & 3;                         // head scalar count

    // ---- stage ids (phase-shifted) + codes ----
    s_ids[p + t * 10] = (j == 0) ? -1.0f : 128.0f;         // sep of face j-1 / lead pad
    #pragma unroll
    for (int k = 0; k < 9; ++k) {
        s_ids[p + t * 10 + 1 + k] = code_f[k];
        s_codes[t * 9 + k]        = code_f[k];
    }
    __syncthreads();

    float* out_ids  = out + OFF_IDS;
    float* out_mask = out + OFF_MASK;
    float* out_c1   = out + OFF_C1;
    float* out_c2   = out + OFF_C2;
    float* out_rec  = out + OFF_REC;

    // ---- ids + mask: aligned vf4 nt stores ----
    const vf4     ones = {1.0f, 1.0f, 1.0f, 1.0f};
    const size_t  A    = S + pp;                           // 16B-aligned global start
    const int     nf4  = (p == 0) ? 640 : 639;
    const int     lb   = (p == 0) ? 0 : 1;                 // LDS vf4 base index
    const vf4*    s4   = (const vf4*)s_ids;
    vf4* ids4  = (vf4*)(out_ids  + A);
    vf4* mask4 = (vf4*)(out_mask + A);
    for (int f4 = t; f4 < nf4; f4 += 256) {
        __builtin_nontemporal_store(s4[lb + f4], ids4 + f4);
        __builtin_nontemporal_store(ones,        mask4 + f4);
    }
    if (t < pp) {                                          // head scalars
        out_ids [S + t] = s_ids[p + t];
        out_mask[S + t] = 1.0f;
    }
    if (t >= 4 && t < 4 + p) {                             // tail scalars
        const int m = t - 4;
        out_ids [S + 2560 - p + m] = s_ids[2560 + m];
        out_mask[S + 2560 - p + m] = 1.0f;
    }

    // ---- codes x2: naturally 16B-aligned ----
    const size_t baseC = ((size_t)b * NF_ + j0) * 9;       // multiple of 4
    const vf4* sc4 = (const vf4*)s_codes;
    vf4* c1p = (vf4*)(out_c1 + baseC);
    vf4* c2p = (vf4*)(out_c2 + baseC);
    for (int f4 = t; f4 < 576; f4 += 256) {
        vf4 v = sc4[f4];
        __builtin_nontemporal_store(v, c1p + f4);
        __builtin_nontemporal_store(v, c2p + f4);
    }

    // ---- final pad + recon_faces ----
    if (t == 0) {
        if (j0 == NF_ - 256) {
            out_ids [(size_t)b * ROW_ + (ROW_ - 1)] = -1.0f;
            out_mask[(size_t)b * ROW_ + (ROW_ - 1)] = 1.0f;
        }
        if (j0 == 0) {  // thread 0 of first block holds face 0's codes
            #pragma unroll
            for (int k = 0; k < 9; ++k)
                out_rec[b * 9 + k] = (code_f[k] + 0.5f) * 0.015625f - 1.0f;
        }
    }
}

extern "C" void kernel_launch(void* const* d_in, const int* in_sizes, int n_in,
                              void* d_out, int out_size, void* d_ws, size_t ws_size,
                              hipStream_t stream) {
    const float* verts = (const float*)d_in[0];
    const int*   faces = (const int*)d_in[1];
    float*       out   = (float*)d_out;

    mesh_tok_kernel<<<dim3(B_ * (NF_ / 256)), dim3(256), 0, stream>>>(verts, faces, out);
}

// Round 4
// 185.569 us; speedup vs baseline: 1.0259x; 1.0259x over previous
//
#include <hip/hip_runtime.h>

// MeshTokenizer: B=64, NV=8192, NF=16384.
// Outputs concatenated flat as float32:
//   [0] input_ids        64 x 163841   @ 0
//   [1] attention_mask   64 x 163841   @ 10485824
//   [2] codes            64x16384x3x3  @ 20971648
//   [3] discrete_face_coords (==codes) @ 30408832
//   [4] recon_faces      64x1x3x3      @ 39846016
// 159.4 MB writes + ~19 MB reads -> ~28 us write-roofline @6.3 TB/s.
//
// R4 restructure: two-pass. Pass A packs each vertex's 3 discretized codes
// into one uint (7b each) -> 2 MB table in d_ws (32 KB/batch -> L1-resident).
// Pass B gathers 3 dwords/face instead of 9 floats (3x fewer scatter reqs).

#define B_      64
#define NV_     8192
#define NF_     16384
#define ROW_    (NF_ * 10 + 1)   // 163841 (odd stride -> per-batch dword phase b&3)
#define OFF_IDS   ((size_t)0)
#define OFF_MASK  ((size_t)10485824)
#define OFF_C1    ((size_t)20971648)
#define OFF_C2    ((size_t)30408832)
#define OFF_REC   ((size_t)39846016)

typedef float vf4 __attribute__((ext_vector_type(4)));

__device__ __forceinline__ float disc1(float x) {
    // (x-LO)/(HI-LO)*128 - 0.5 == (x+1)*64 - 0.5 bit-exactly; round-half-even
    float r = rintf((x + 1.0f) * 64.0f - 0.5f);
    return fminf(fmaxf(r, 0.0f), 127.0f);
}

// ---- Pass A: per-vertex discretize + pack (64*8192 = 524288 verts) ----
__global__ __launch_bounds__(256) void pack_verts_kernel(
        const float* __restrict__ verts,
        unsigned int* __restrict__ packed) {
    const int g = blockIdx.x * 256 + threadIdx.x;       // global vertex id
    const float* vp = verts + (size_t)g * 3;
    const unsigned int c0 = (unsigned int)disc1(vp[0]);
    const unsigned int c1 = (unsigned int)disc1(vp[1]);
    const unsigned int c2 = (unsigned int)disc1(vp[2]);
    packed[g] = c0 | (c1 << 8) | (c2 << 16);
}

// ---- Pass B: one block = 256 consecutive faces of one batch ----
// Thread t (face j) owns input_ids [j*10, j*10+9]: pos j*10 = sep of face j-1
// (or lead pad), then the 9 tokens. Block span = contiguous 2560 floats at
// S = b*163841 + j0*10; phase p = S&3 baked into LDS so global stores are
// 16B-aligned dwordx4 nt; <=3 head + <=3 tail elems scalar.
__global__ __launch_bounds__(256) void mesh_tok_kernel(
        const unsigned int* __restrict__ packed,
        const int*          __restrict__ faces,
        float*              __restrict__ out) {
    const int t   = threadIdx.x;
    const int blk = blockIdx.x;
    const int b   = blk >> 6;            // batch
    const int j0  = (blk & 63) << 8;     // first face of this block
    const int j   = j0 + t;

    __shared__ __align__(16) float s_ids[2564];
    __shared__ __align__(16) float s_codes[2304];

    // ---- face indices + packed-code gather (3 dwords, 32KB/batch table) ----
    const int* fp = faces + ((size_t)b * NF_ + j) * 3;
    const unsigned int* pb = packed + (size_t)b * NV_;
    float code_f[9];
    #pragma unroll
    for (int vi = 0; vi < 3; ++vi) {
        const unsigned int pk = pb[fp[vi]];
        code_f[vi * 3 + 0] = (float)(pk & 127u);
        code_f[vi * 3 + 1] = (float)((pk >> 8) & 127u);
        code_f[vi * 3 + 2] = (float)((pk >> 16) & 127u);
    }

    const size_t S  = (size_t)b * ROW_ + (size_t)j0 * 10;
    const int    p  = (int)(S & 3);                        // == b & 3
    const int    pp = (4 - p) & 3;

    // ---- stage ids (phase-shifted) + codes ----
    s_ids[p + t * 10] = (j == 0) ? -1.0f : 128.0f;
    #pragma unroll
    for (int k = 0; k < 9; ++k) {
        s_ids[p + t * 10 + 1 + k] = code_f[k];
        s_codes[t * 9 + k]        = code_f[k];
    }
    __syncthreads();

    float* out_ids  = out + OFF_IDS;
    float* out_mask = out + OFF_MASK;
    float* out_c1   = out + OFF_C1;
    float* out_c2   = out + OFF_C2;
    float* out_rec  = out + OFF_REC;

    // ---- ids + mask: aligned vf4 nt stores ----
    const vf4     ones = {1.0f, 1.0f, 1.0f, 1.0f};
    const size_t  A    = S + pp;
    const int     nf4  = (p == 0) ? 640 : 639;
    const int     lb   = (p == 0) ? 0 : 1;
    const vf4*    s4   = (const vf4*)s_ids;
    vf4* ids4  = (vf4*)(out_ids  + A);
    vf4* mask4 = (vf4*)(out_mask + A);
    for (int f4 = t; f4 < nf4; f4 += 256) {
        __builtin_nontemporal_store(s4[lb + f4], ids4 + f4);
        __builtin_nontemporal_store(ones,        mask4 + f4);
    }
    if (t < pp) {
        out_ids [S + t] = s_ids[p + t];
        out_mask[S + t] = 1.0f;
    }
    if (t >= 4 && t < 4 + p) {
        const int m = t - 4;
        out_ids [S + 2560 - p + m] = s_ids[2560 + m];
        out_mask[S + 2560 - p + m] = 1.0f;
    }

    // ---- codes x2: naturally 16B-aligned ----
    const size_t baseC = ((size_t)b * NF_ + j0) * 9;
    const vf4* sc4 = (const vf4*)s_codes;
    vf4* c1p = (vf4*)(out_c1 + baseC);
    vf4* c2p = (vf4*)(out_c2 + baseC);
    for (int f4 = t; f4 < 576; f4 += 256) {
        vf4 v = sc4[f4];
        __builtin_nontemporal_store(v, c1p + f4);
        __builtin_nontemporal_store(v, c2p + f4);
    }

    // ---- final pad + recon_faces ----
    if (t == 0) {
        if (j0 == NF_ - 256) {
            out_ids [(size_t)b * ROW_ + (ROW_ - 1)] = -1.0f;
            out_mask[(size_t)b * ROW_ + (ROW_ - 1)] = 1.0f;
        }
        if (j0 == 0) {  // thread 0 of first block holds face 0's codes
            #pragma unroll
            for (int k = 0; k < 9; ++k)
                out_rec[b * 9 + k] = (code_f[k] + 0.5f) * 0.015625f - 1.0f;
        }
    }
}

extern "C" void kernel_launch(void* const* d_in, const int* in_sizes, int n_in,
                              void* d_out, int out_size, void* d_ws, size_t ws_size,
                              hipStream_t stream) {
    const float*  verts  = (const float*)d_in[0];
    const int*    faces  = (const int*)d_in[1];
    float*        out    = (float*)d_out;
    unsigned int* packed = (unsigned int*)d_ws;   // 2 MB: 64*8192 uints

    pack_verts_kernel<<<dim3(B_ * NV_ / 256), dim3(256), 0, stream>>>(verts, packed);
    mesh_tok_kernel  <<<dim3(B_ * (NF_ / 256)), dim3(256), 0, stream>>>(packed, faces, out);
}